// Round 3
// baseline (144.507 us; speedup 1.0000x reference)
//
#include <hip/hip_runtime.h>

// Problem constants: N=4, C=320, H=W=D=16 -> L=4096, POS_RATIO=0.5
#define LVOX   4096
#define NCH    320
#define NCOMBO 8        // 4 batches x 2 branches (normal, batch-flipped q)
#define NSEG   64       // enum waves per combo (4096 threads / 64 lanes)
#define SEGCAP 4096     // run slots per segment (worst case ~36 runs/thread * 64 = 2304)
#define PKSTR  17       // prefix-sum entries per (x,y) cell (exclusive, 0..16)
#define PKROW  (256 * PKSTR)
// ws layout (every consumed word deterministically written, no zeroing needed):
//   wcnt  [8*64] u32        @ 0
//   wpcnt [8*64] u32        @ 2048
//   Spart [8*NCH] f32       @ 4096
//   tick  [1] u32           @ 14336   (completion ticket, zeroed by enum_runs)
//   runs  [8*64*SEGCAP] u32 @ 16384   (8 MB, per-segment lists)
#define WPCNT_OFF 2048
#define SPART_OFF 4096
#define TICK_OFF  14336
#define RUNS_OFF  16384

struct Geo {
    float qs0, qs1, qs2, qo0, qo1, qo2;
    float ks0, ks1, ks2, ko0, ko1, ko2;
    float ik0, ik1, ik2;
    float T;
};

// max_diag uses UNFLIPPED diag_q[n] even in the flipped branch (ref computes it pre-flip).
__device__ __forceinline__ Geo make_geo(const float* __restrict__ cq,
                                        const float* __restrict__ ck,
                                        int n, int qb) {
    Geo g;
    const float* qc = cq + qb * 6;
    const float* qn = cq + n * 6;
    const float* kc = ck + n * 6;
    g.qs0 = (qc[3] - qc[0]) * (1.f / 16.f); g.qo0 = qc[0];
    g.qs1 = (qc[4] - qc[1]) * (1.f / 16.f); g.qo1 = qc[1];
    g.qs2 = (qc[5] - qc[2]) * (1.f / 16.f); g.qo2 = qc[2];
    g.ks0 = (kc[3] - kc[0]) * (1.f / 16.f); g.ko0 = kc[0];
    g.ks1 = (kc[4] - kc[1]) * (1.f / 16.f); g.ko1 = kc[1];
    g.ks2 = (kc[5] - kc[2]) * (1.f / 16.f); g.ko2 = kc[2];
    g.ik0 = 1.f / g.ks0; g.ik1 = 1.f / g.ks1; g.ik2 = 1.f / g.ks2;
    float b0 = (qn[3] - qn[0]) * (1.f / 16.f);
    float b1 = (qn[4] - qn[1]) * (1.f / 16.f);
    float b2 = (qn[5] - qn[2]) * (1.f / 16.f);
    float dq = sqrtf(b0 * b0 + b1 * b1 + b2 * b2);
    float dk = sqrtf(g.ks0 * g.ks0 + g.ks1 * g.ks1 + g.ks2 * g.ks2);
    g.T = 0.5f * fmaxf(dq, dk);
    return g;
}

__device__ __forceinline__ void axrange(float c, float ko, float ik, float T,
                                        int& m0, int& m1) {
    float lo = (c - T - ko) * ik - 0.5f;
    float hi = (c + T - ko) * ik - 0.5f;
    m0 = max((int)ceilf(lo) - 1, 0);
    m1 = min((int)floorf(hi) + 1, 15);
}

// One THREAD per (combo, l); emits one RUN per masked (x,y) cell:
//   record = (l<<17) | ((len-1)<<13) | (cell*17 + zf),  cell = (x<<4)|y
// Exact per-z sqrtf(...)<T test -> mask identical to reference.
// Wave (= block, 64 threads) of combo j owns segment (j*64+w): runs via
// in-wave prefix scan, counts via plain stores. NO pre-zeroing.
// Thread gid==0 also zeroes the gather completion ticket (stream order
// guarantees it lands before gather starts).
__global__ void enum_runs(const float* __restrict__ coord_q,
                          const float* __restrict__ coord_k,
                          unsigned* __restrict__ wcnt,
                          unsigned* __restrict__ wpcnt,
                          unsigned* __restrict__ runs,
                          unsigned* __restrict__ tick) {
    int gid = blockIdx.x * 64 + threadIdx.x;    // 8*4096 threads, 512 blocks
    if (gid == 0) tick[0] = 0u;
    int j = gid >> 12;
    int l = gid & 4095;
    int seg = j * NSEG + ((gid & 4095) >> 6);   // wave-uniform
    int n = j & 3;
    int qb = (j & 4) ? (3 - n) : n;
    Geo g = make_geo(coord_q, coord_k, n, qb);

    int ix = l >> 8, iy = (l >> 4) & 15, iz = l & 15;
    float cx = (ix + 0.5f) * g.qs0 + g.qo0;
    float cy = (iy + 0.5f) * g.qs1 + g.qo1;
    float cz = (iz + 0.5f) * g.qs2 + g.qo2;
    int x0, x1, y0, y1, z0, z1;
    axrange(cx, g.ko0, g.ik0, g.T, x0, x1);
    axrange(cy, g.ko1, g.ik1, g.T, y0, y1);
    axrange(cz, g.ko2, g.ik2, g.T, z0, z1);

    // pass 1: count runs and hits
    int nh = 0, nr = 0;
    for (int x = x0; x <= x1; ++x) {
        float dx = cx - ((x + 0.5f) * g.ks0 + g.ko0);
        float dx2 = dx * dx;
        for (int y = y0; y <= y1; ++y) {
            float dy = cy - ((y + 0.5f) * g.ks1 + g.ko1);
            float dxy = dx2 + dy * dy;
            int zc = 0;
            for (int z = z0; z <= z1; ++z) {
                float dz = cz - ((z + 0.5f) * g.ks2 + g.ko2);
                if (sqrtf(dxy + dz * dz) < g.T) zc++;
            }
            if (zc) { nr++; nh += zc; }
        }
    }

    // in-wave exclusive position via inclusive shuffle scan
    int lane = threadIdx.x & 63;
    int incl = nr;
#pragma unroll
    for (int off = 1; off < 64; off <<= 1) {
        int t = __shfl_up(incl, off, 64);
        if (lane >= off) incl += t;
    }
    int w = incl - nr;                          // exclusive prefix within segment
    if (lane == 63) wcnt[seg] = (unsigned)incl; // total runs in segment

    int hsum = nh;
#pragma unroll
    for (int off = 32; off; off >>= 1) hsum += __shfl_down(hsum, off, 64);
    if (lane == 0) wpcnt[seg] = (unsigned)hsum; // total hits in segment

    // pass 2: write runs
    unsigned* out = runs + (size_t)seg * SEGCAP;
    for (int x = x0; x <= x1; ++x) {
        float dx = cx - ((x + 0.5f) * g.ks0 + g.ko0);
        float dx2 = dx * dx;
        for (int y = y0; y <= y1; ++y) {
            float dy = cy - ((y + 0.5f) * g.ks1 + g.ko1);
            float dxy = dx2 + dy * dy;
            int zf = -1, zc = 0;
            for (int z = z0; z <= z1; ++z) {
                float dz = cz - ((z + 0.5f) * g.ks2 + g.ko2);
                if (sqrtf(dxy + dz * dz) < g.T) { if (!zc) zf = z; zc++; }
            }
            if (zc) {
                if (w < SEGCAP)
                    out[w] = ((unsigned)l << 17)
                           | ((unsigned)(zc - 1) << 13)
                           | (unsigned)(((x << 4) | y) * PKSTR + zf);
                w++;
            }
        }
    }
}

// Gather, q-split for occupancy: block (bx, c), bx = g*2+qi. Group g=0 ->
// batches {0,3}, g=1 -> {1,2}; the block stages ONE q row (batch qi of the
// group) + BOTH k rows as per-(x,y)-cell exclusive z-prefix sums (stride 17).
// It computes the 2 combos using that q row:
//   qi=0 -> {n0 (k[n0]), 4+n1 (k[n1])};  qi=1 -> {n1 (k[n1]), 4+n0 (k[n0])}.
// LDS = 16KB q + 34.8KB pk + red ~= 51KB -> 3 blocks/CU; grid 4x320 = 1280.
// 8 threads per segment, uint4 = 4 records per iteration, 1-deep prefetch.
// R11: compact reverted (measured +4.2us regression); finalize FUSED here via
// last-block ticket (-1 launch, -1 gap): after the Spart store each block
// fences + takes a ticket; ticket 1279 re-reads Spart (10KB, L2-hot) + wpcnt
// and writes out[0]. Launch count is now 2 (was 4).
__global__ void __launch_bounds__(512) gather_fused(
        const float* __restrict__ q, const float* __restrict__ k,
        const unsigned* __restrict__ wcnt, const unsigned* __restrict__ runs,
        float* __restrict__ Spart, const unsigned* __restrict__ wpcnt,
        unsigned* __restrict__ tick, float* __restrict__ outp) {
    // sh layout: qr[4096] | pkA[PKROW] | pkB[PKROW] | sred[16]
    __shared__ float sh[LVOX + 2 * PKROW + 16];
    __shared__ unsigned lastflag;
    __shared__ float tj[NCOMBO];
    const int QR = 0, PK = LVOX, SR = LVOX + 2 * PKROW;

    int bx = blockIdx.x;             // 0..3
    int c  = blockIdx.y;
    int g  = bx >> 1, qi = bx & 1;
    int n0 = g ? 1 : 0;
    int n1 = 3 - n0;
    int qn = qi ? n1 : n0;           // batch of the staged q row
    int t = threadIdx.x;

    // stage q row (coalesced float4): 4096 floats, 512 thr x 2 iters
    const float* qsrc = q + ((size_t)(qn * NCH + c)) * LVOX;
#pragma unroll
    for (int i = 0; i < 2; ++i) {
        int off = (t + 512 * i) * 4;
        *(float4*)&sh[QR + off] = *(const float4*)&qsrc[off];
    }

    // stage k rows as exclusive z-prefix per cell: thread t owns one cell
    {
        int row = t >> 8;            // 0 -> k[n0], 1 -> k[n1]
        int cl  = t & 255;
        const float* ks = k + ((size_t)((row ? n1 : n0) * NCH + c)) * LVOX + cl * 16;
        float4 v0 = *(const float4*)&ks[0];
        float4 v1 = *(const float4*)&ks[4];
        float4 v2 = *(const float4*)&ks[8];
        float4 v3 = *(const float4*)&ks[12];
        float vv[16] = {v0.x, v0.y, v0.z, v0.w, v1.x, v1.y, v1.z, v1.w,
                        v2.x, v2.y, v2.z, v2.w, v3.x, v3.y, v3.z, v3.w};
        float* dst = &sh[PK + row * PKROW + cl * PKSTR];
        float e = 0.f;
        dst[0] = 0.f;
#pragma unroll
        for (int i = 0; i < 16; ++i) { e += vv[i]; dst[i + 1] = e; }
    }
    __syncthreads();

    // combos for this block (see header comment)
    const int jl[2] = {qi ? n1 : n0, 4 + (qi ? n0 : n1)};
    const int kr[2] = {qi ? 1 : 0, qi ? 0 : 1};          // pk row per combo
    float accv[2];

    int G    = t >> 3;                         // 0..63: thread group
    int segi = ((G & 7) << 3) | (G >> 3);      // transposed map: x-slab spread
    int tin  = t & 7;                          // 8 threads per segment

#pragma unroll
    for (int ci = 0; ci < 2; ++ci) {
        int j = jl[ci];
        unsigned cnt = wcnt[j * NSEG + segi];
        if (cnt > SEGCAP) cnt = SEGCAP;
        const unsigned* rl = runs + (size_t)(j * NSEG + segi) * SEGCAP;
        const float* pkb = &sh[PK + kr[ci] * PKROW];
        float acc = 0.f;
        unsigned p = (unsigned)tin * 4u;
        if (p < cnt) {
            uint4 r4 = *(const uint4*)&rl[p];   // p%4==0, p+3 < SEGCAP -> in-bounds
            while (true) {
                unsigned pn = p + 32u;
                uint4 nx;
                if (pn < cnt) nx = *(const uint4*)&rl[pn];   // 1-deep prefetch
                unsigned rr[4] = {r4.x, r4.y, r4.z, r4.w};
#pragma unroll
                for (int e = 0; e < 4; ++e) {
                    bool valid = (p + (unsigned)e) < cnt;
                    unsigned pr = rr[e];
                    int idx  = (int)(pr & 8191u);           // cell*17 + zf
                    int lenm = (int)((pr >> 13) & 15u);     // len-1
                    int l    = (int)(pr >> 17);
                    float s = pkb[idx + lenm + 1] - pkb[idx];
                    acc += valid ? sh[QR + l] * s : 0.f;
                }
                if (pn >= cnt) break;
                r4 = nx; p = pn;
            }
        }
        accv[ci] = acc;
    }

    int wv = t >> 6, lane = t & 63;
#pragma unroll
    for (int ci = 0; ci < 2; ++ci) {
        float a = accv[ci];
#pragma unroll
        for (int off = 32; off; off >>= 1) a += __shfl_down(a, off, 64);
        if (lane == 0) sh[SR + wv * 2 + ci] = a;
    }
    __syncthreads();
    if (t < 2) {
        float v = 0.f;
#pragma unroll
        for (int w = 0; w < 8; ++w) v += sh[SR + w * 2 + t];
        Spart[(size_t)jl[t] * NCH + c] = v;   // unique writer per (combo, channel)
    }
    __syncthreads();

    // ---- fused finalize: last block to finish does the global reduction ----
    if (t == 0) {
        __threadfence();                       // publish Spart before ticket
        unsigned old = atomicAdd(tick, 1u);
        lastflag = (old == 4u * NCH - 1u) ? 1u : 0u;
    }
    __syncthreads();
    if (lastflag) {
        __threadfence();                       // order reads after ticket win
        int j8 = t >> 6;                       // 8 combos x 64 lanes
        int s  = t & 63;
        float v = 0.f;
        for (int i = s; i < NCH; i += 64)
            v += Spart[(size_t)j8 * NCH + i];
        float pcf = (float)wpcnt[j8 * NSEG + s];
#pragma unroll
        for (int off = 32; off; off >>= 1) {
            v   += __shfl_down(v, off, 64);
            pcf += __shfl_down(pcf, off, 64);
        }
        if (s == 0) tj[j8] = v / (pcf + 1e-6f);
        __syncthreads();
        if (t == 0) {
            float tt = 0.f;
#pragma unroll
            for (int jj = 0; jj < NCOMBO; ++jj) tt += tj[jj];
            outp[0] = -0.5f * tt;   // -2*mean over 4 batches, x2 branches
        }
    }
}

extern "C" void kernel_launch(void* const* d_in, const int* in_sizes, int n_in,
                              void* d_out, int out_size, void* d_ws, size_t ws_size,
                              hipStream_t stream) {
    const float* q       = (const float*)d_in[0];
    const float* k       = (const float*)d_in[1];
    const float* coord_q = (const float*)d_in[2];
    const float* coord_k = (const float*)d_in[3];
    float* out = (float*)d_out;

    unsigned* wcnt  = (unsigned*)d_ws;
    unsigned* wpcnt = (unsigned*)((char*)d_ws + WPCNT_OFF);
    float*    Spart = (float*)((char*)d_ws + SPART_OFF);
    unsigned* tick  = (unsigned*)((char*)d_ws + TICK_OFF);
    unsigned* runs  = (unsigned*)((char*)d_ws + RUNS_OFF);
    // total ws use ~8.1 MB; every consumed word is written before read.

    enum_runs<<<(NCOMBO * LVOX) / 64, 64, 0, stream>>>(coord_q, coord_k, wcnt, wpcnt, runs, tick);
    gather_fused<<<dim3(4, NCH), 512, 0, stream>>>(q, k, wcnt, runs, Spart, wpcnt, tick, out);
}

// Round 4
// 119.534 us; speedup vs baseline: 1.2089x; 1.2089x over previous
//
#include <hip/hip_runtime.h>

// Problem constants: N=4, C=320, H=W=D=16 -> L=4096, POS_RATIO=0.5
#define LVOX   4096
#define NCH    320
#define NCOMBO 8        // 4 batches x 2 branches (normal, batch-flipped q)
#define NSEG   64       // enum waves per combo (4096 threads / 64 lanes)
#define SEGCAP 4096     // run slots per segment (worst case ~36 runs/thread * 64 = 2304)
#define PKSTR  17       // prefix-sum entries per (x,y) cell (exclusive, 0..16)
#define PKROW  (256 * PKSTR)
// ws layout (every consumed word deterministically written, no zeroing needed):
//   wcnt  [8*64] u32        @ 0
//   wpcnt [8*64] u32        @ 2048
//   Spart [8*NCH] f32       @ 4096    (one writer block per (combo, channel))
//   runs  [8*64*SEGCAP] u32 @ 16384   (8 MB)
#define WPCNT_OFF 2048
#define SPART_OFF 4096
#define RUNS_OFF  16384

struct Geo {
    float qs0, qs1, qs2, qo0, qo1, qo2;
    float ks0, ks1, ks2, ko0, ko1, ko2;
    float ik0, ik1, ik2;
    float T;
};

// max_diag uses UNFLIPPED diag_q[n] even in the flipped branch (ref computes it pre-flip).
__device__ __forceinline__ Geo make_geo(const float* __restrict__ cq,
                                        const float* __restrict__ ck,
                                        int n, int qb) {
    Geo g;
    const float* qc = cq + qb * 6;
    const float* qn = cq + n * 6;
    const float* kc = ck + n * 6;
    g.qs0 = (qc[3] - qc[0]) * (1.f / 16.f); g.qo0 = qc[0];
    g.qs1 = (qc[4] - qc[1]) * (1.f / 16.f); g.qo1 = qc[1];
    g.qs2 = (qc[5] - qc[2]) * (1.f / 16.f); g.qo2 = qc[2];
    g.ks0 = (kc[3] - kc[0]) * (1.f / 16.f); g.ko0 = kc[0];
    g.ks1 = (kc[4] - kc[1]) * (1.f / 16.f); g.ko1 = kc[1];
    g.ks2 = (kc[5] - kc[2]) * (1.f / 16.f); g.ko2 = kc[2];
    g.ik0 = 1.f / g.ks0; g.ik1 = 1.f / g.ks1; g.ik2 = 1.f / g.ks2;
    float b0 = (qn[3] - qn[0]) * (1.f / 16.f);
    float b1 = (qn[4] - qn[1]) * (1.f / 16.f);
    float b2 = (qn[5] - qn[2]) * (1.f / 16.f);
    float dq = sqrtf(b0 * b0 + b1 * b1 + b2 * b2);
    float dk = sqrtf(g.ks0 * g.ks0 + g.ks1 * g.ks1 + g.ks2 * g.ks2);
    g.T = 0.5f * fmaxf(dq, dk);
    return g;
}

__device__ __forceinline__ void axrange(float c, float ko, float ik, float T,
                                        int& m0, int& m1) {
    float lo = (c - T - ko) * ik - 0.5f;
    float hi = (c + T - ko) * ik - 0.5f;
    m0 = max((int)ceilf(lo) - 1, 0);
    m1 = min((int)floorf(hi) + 1, 15);
}

// One THREAD per (combo, l); emits one RUN per masked (x,y) cell:
//   record = (l<<17) | ((len-1)<<13) | (cell*17 + zf),  cell = (x<<4)|y
// Exact per-z sqrtf(...)<T test -> mask identical to reference.
// Wave (= block, 64 threads) of combo j owns segment (j*64+w): runs via
// in-wave prefix scan, counts via plain stores. NO atomics, NO pre-zeroing.
__global__ void enum_runs(const float* __restrict__ coord_q,
                          const float* __restrict__ coord_k,
                          unsigned* __restrict__ wcnt,
                          unsigned* __restrict__ wpcnt,
                          unsigned* __restrict__ runs) {
    int gid = blockIdx.x * 64 + threadIdx.x;    // 8*4096 threads, 512 blocks
    int j = gid >> 12;
    int l = gid & 4095;
    int seg = j * NSEG + ((gid & 4095) >> 6);   // wave-uniform
    int n = j & 3;
    int qb = (j & 4) ? (3 - n) : n;
    Geo g = make_geo(coord_q, coord_k, n, qb);

    int ix = l >> 8, iy = (l >> 4) & 15, iz = l & 15;
    float cx = (ix + 0.5f) * g.qs0 + g.qo0;
    float cy = (iy + 0.5f) * g.qs1 + g.qo1;
    float cz = (iz + 0.5f) * g.qs2 + g.qo2;
    int x0, x1, y0, y1, z0, z1;
    axrange(cx, g.ko0, g.ik0, g.T, x0, x1);
    axrange(cy, g.ko1, g.ik1, g.T, y0, y1);
    axrange(cz, g.ko2, g.ik2, g.T, z0, z1);

    // pass 1: count runs and hits
    int nh = 0, nr = 0;
    for (int x = x0; x <= x1; ++x) {
        float dx = cx - ((x + 0.5f) * g.ks0 + g.ko0);
        float dx2 = dx * dx;
        for (int y = y0; y <= y1; ++y) {
            float dy = cy - ((y + 0.5f) * g.ks1 + g.ko1);
            float dxy = dx2 + dy * dy;
            int zc = 0;
            for (int z = z0; z <= z1; ++z) {
                float dz = cz - ((z + 0.5f) * g.ks2 + g.ko2);
                if (sqrtf(dxy + dz * dz) < g.T) zc++;
            }
            if (zc) { nr++; nh += zc; }
        }
    }

    // in-wave exclusive position via inclusive shuffle scan
    int lane = threadIdx.x & 63;
    int incl = nr;
#pragma unroll
    for (int off = 1; off < 64; off <<= 1) {
        int t = __shfl_up(incl, off, 64);
        if (lane >= off) incl += t;
    }
    int w = incl - nr;                          // exclusive prefix within segment
    if (lane == 63) wcnt[seg] = (unsigned)incl; // total runs in segment

    int hsum = nh;
#pragma unroll
    for (int off = 32; off; off >>= 1) hsum += __shfl_down(hsum, off, 64);
    if (lane == 0) wpcnt[seg] = (unsigned)hsum; // total hits in segment

    // pass 2: write runs
    unsigned* out = runs + (size_t)seg * SEGCAP;
    for (int x = x0; x <= x1; ++x) {
        float dx = cx - ((x + 0.5f) * g.ks0 + g.ko0);
        float dx2 = dx * dx;
        for (int y = y0; y <= y1; ++y) {
            float dy = cy - ((y + 0.5f) * g.ks1 + g.ko1);
            float dxy = dx2 + dy * dy;
            int zf = -1, zc = 0;
            for (int z = z0; z <= z1; ++z) {
                float dz = cz - ((z + 0.5f) * g.ks2 + g.ko2);
                if (sqrtf(dxy + dz * dz) < g.T) { if (!zc) zf = z; zc++; }
            }
            if (zc) {
                if (w < SEGCAP)
                    out[w] = ((unsigned)l << 17)
                           | ((unsigned)(zc - 1) << 13)
                           | (unsigned)(((x << 4) | y) * PKSTR + zf);
                w++;
            }
        }
    }
}

// Gather, q-split for occupancy: block (bx, c), bx = g*2+qi. Group g=0 ->
// batches {0,3}, g=1 -> {1,2}; the block stages ONE q row (batch qi of the
// group) + BOTH k rows as per-(x,y)-cell exclusive z-prefix sums (stride 17).
// It computes the 2 combos using that q row:
//   qi=0 -> {n0 (k[n0]), 4+n1 (k[n1])};  qi=1 -> {n1 (k[n1]), 4+n0 (k[n0])}.
// LDS = 16KB q + 34.8KB pk + red ~= 51KB -> 3 blocks/CU; grid 4x320 = 1280.
// 8 threads per segment, uint4 = 4 records per iteration.
// R12: fused finalize REVERTED (measured +24us: 1280 same-address atomics +
// per-block threadfence serialize cross-XCD). Counters showed gather is
// LATENCY-bound (VALUBusy 12%, HBM 7.5%, occ 44%): ~22 dependent L2/L3 quad
// loads per thread, 1-deep prefetch, only ~3.5 waves/SIMD. Fix: 4-deep
// register pipeline (b0..b3 explicitly named, no runtime indexing) ->
// exposed load latency / 4.
__global__ void __launch_bounds__(512) gather_fused(
        const float* __restrict__ q, const float* __restrict__ k,
        const unsigned* __restrict__ wcnt, const unsigned* __restrict__ runs,
        float* __restrict__ Spart) {
    // sh layout: qr[4096] | pkA[PKROW] | pkB[PKROW] | sred[16]
    __shared__ float sh[LVOX + 2 * PKROW + 16];
    const int QR = 0, PK = LVOX, SR = LVOX + 2 * PKROW;

    int bx = blockIdx.x;             // 0..3
    int c  = blockIdx.y;
    int g  = bx >> 1, qi = bx & 1;
    int n0 = g ? 1 : 0;
    int n1 = 3 - n0;
    int qn = qi ? n1 : n0;           // batch of the staged q row
    int t = threadIdx.x;

    // stage q row (coalesced float4): 4096 floats, 512 thr x 2 iters
    const float* qsrc = q + ((size_t)(qn * NCH + c)) * LVOX;
#pragma unroll
    for (int i = 0; i < 2; ++i) {
        int off = (t + 512 * i) * 4;
        *(float4*)&sh[QR + off] = *(const float4*)&qsrc[off];
    }

    // stage k rows as exclusive z-prefix per cell: thread t owns one cell
    {
        int row = t >> 8;            // 0 -> k[n0], 1 -> k[n1]
        int cl  = t & 255;
        const float* ks = k + ((size_t)((row ? n1 : n0) * NCH + c)) * LVOX + cl * 16;
        float4 v0 = *(const float4*)&ks[0];
        float4 v1 = *(const float4*)&ks[4];
        float4 v2 = *(const float4*)&ks[8];
        float4 v3 = *(const float4*)&ks[12];
        float vv[16] = {v0.x, v0.y, v0.z, v0.w, v1.x, v1.y, v1.z, v1.w,
                        v2.x, v2.y, v2.z, v2.w, v3.x, v3.y, v3.z, v3.w};
        float* dst = &sh[PK + row * PKROW + cl * PKSTR];
        float e = 0.f;
        dst[0] = 0.f;
#pragma unroll
        for (int i = 0; i < 16; ++i) { e += vv[i]; dst[i + 1] = e; }
    }
    __syncthreads();

    // combos for this block (see header comment)
    const int jl[2] = {qi ? n1 : n0, 4 + (qi ? n0 : n1)};
    const int kr[2] = {qi ? 1 : 0, qi ? 0 : 1};          // pk row per combo
    float accv[2];

    int G    = t >> 3;                         // 0..63: thread group
    int segi = ((G & 7) << 3) | (G >> 3);      // transposed map: x-slab spread
    int tin  = t & 7;                          // 8 threads per segment

#pragma unroll
    for (int ci = 0; ci < 2; ++ci) {
        int j = jl[ci];
        unsigned cnt = wcnt[j * NSEG + segi];
        if (cnt > SEGCAP) cnt = SEGCAP;
        const unsigned* rl = runs + (size_t)(j * NSEG + segi) * SEGCAP;
        const float* pkb = &sh[PK + kr[ci] * PKROW];
        float acc = 0.f;

        // 4-deep register pipeline over the quad stream (stride 32 records).
        // Quads are loaded only when their base < cnt; unloaded slots stay
        // zero-initialized and their elements are discarded by `valid`.
        unsigned p0 = (unsigned)tin * 4u;
        uint4 b0 = make_uint4(0u, 0u, 0u, 0u), b1 = b0, b2 = b0, b3 = b0;
        if (p0       < cnt) b0 = *(const uint4*)&rl[p0];
        if (p0 + 32u < cnt) b1 = *(const uint4*)&rl[p0 + 32u];
        if (p0 + 64u < cnt) b2 = *(const uint4*)&rl[p0 + 64u];
        if (p0 + 96u < cnt) b3 = *(const uint4*)&rl[p0 + 96u];
        for (unsigned p = p0; p < cnt; p += 32u) {
            unsigned rr[4] = {b0.x, b0.y, b0.z, b0.w};
            // rotate pipeline and issue refill for p+128 immediately
            b0 = b1; b1 = b2; b2 = b3;
            unsigned pn = p + 128u;
            if (pn < cnt) b3 = *(const uint4*)&rl[pn];
#pragma unroll
            for (int e = 0; e < 4; ++e) {
                bool valid = (p + (unsigned)e) < cnt;
                unsigned pr = rr[e];
                int idx  = (int)(pr & 8191u);           // cell*17 + zf
                int lenm = (int)((pr >> 13) & 15u);     // len-1
                int l    = (int)(pr >> 17);
                float s = pkb[idx + lenm + 1] - pkb[idx];
                acc += valid ? sh[QR + l] * s : 0.f;
            }
        }
        accv[ci] = acc;
    }

    int wv = t >> 6, lane = t & 63;
#pragma unroll
    for (int ci = 0; ci < 2; ++ci) {
        float a = accv[ci];
#pragma unroll
        for (int off = 32; off; off >>= 1) a += __shfl_down(a, off, 64);
        if (lane == 0) sh[SR + wv * 2 + ci] = a;
    }
    __syncthreads();
    if (t < 2) {
        float v = 0.f;
#pragma unroll
        for (int w = 0; w < 8; ++w) v += sh[SR + w * 2 + t];
        Spart[(size_t)jl[t] * NCH + c] = v;   // unique writer per (combo, channel)
    }
}

// Sum Spart over each combo's 320 slots and wpcnt over 64 segments.
__global__ void finalize(const float* __restrict__ Spart,
                         const unsigned* __restrict__ wpcnt,
                         float* __restrict__ out) {
    __shared__ float tj[NCOMBO];
    int j = threadIdx.x >> 5;      // 8 combos x 32 threads
    int s = threadIdx.x & 31;
    float v = 0.f;
    for (int i = s; i < NCH; i += 32)
        v += Spart[(size_t)j * NCH + i];
    unsigned pc = wpcnt[j * NSEG + s] + wpcnt[j * NSEG + s + 32];
    float pcf = (float)pc;
#pragma unroll
    for (int off = 16; off; off >>= 1) {
        v   += __shfl_down(v, off, 32);
        pcf += __shfl_down(pcf, off, 32);
    }
    if (s == 0) tj[j] = v / (pcf + 1e-6f);
    __syncthreads();
    if (threadIdx.x == 0) {
        float t = 0.f;
#pragma unroll
        for (int jj = 0; jj < NCOMBO; ++jj) t += tj[jj];
        out[0] = -0.5f * t;   // -2*mean over 4 batches, x2 branches
    }
}

extern "C" void kernel_launch(void* const* d_in, const int* in_sizes, int n_in,
                              void* d_out, int out_size, void* d_ws, size_t ws_size,
                              hipStream_t stream) {
    const float* q       = (const float*)d_in[0];
    const float* k       = (const float*)d_in[1];
    const float* coord_q = (const float*)d_in[2];
    const float* coord_k = (const float*)d_in[3];
    float* out = (float*)d_out;

    unsigned* wcnt  = (unsigned*)d_ws;
    unsigned* wpcnt = (unsigned*)((char*)d_ws + WPCNT_OFF);
    float*    Spart = (float*)((char*)d_ws + SPART_OFF);
    unsigned* runs  = (unsigned*)((char*)d_ws + RUNS_OFF);
    // total ws use ~8.1 MB; every consumed word is written before read.

    enum_runs<<<(NCOMBO * LVOX) / 64, 64, 0, stream>>>(coord_q, coord_k, wcnt, wpcnt, runs);
    gather_fused<<<dim3(4, NCH), 512, 0, stream>>>(q, k, wcnt, runs, Spart);
    finalize<<<1, 256, 0, stream>>>(Spart, wpcnt, out);
}